// Round 6
// baseline (206.449 us; speedup 1.0000x reference)
//
#include <hip/hip_runtime.h>

// Problem constants
constexpr int B_ = 32, C_ = 64, H_ = 64, W_ = 64, K_ = 1024;
constexpr int NTOT = B_ * C_ * H_ * W_;          // 8388608 elements of input1/quantized
constexpr int NSP  = B_ * H_ * W_;               // 131072 spatial positions
// d_out float offsets: [0]=loss, [1..32]=input2_KL, [33..33+NTOT)=quantized(BCHW),
// [OFF_ENC .. OFF_ENC+NSP*K)=encodings
constexpr int OFF_Q   = 33;
constexpr int OFF_ENC = OFF_Q + NTOT;            // 8388641  (byte addr == 4 mod 16)
constexpr long long ENC_ELEMS = (long long)NSP * K_;   // 134217728 (2^27)
// Aligned interior: first aligned element e0=3; (ENC_ELEMS-4)/4 quads.
// 3 head + 1 tail elements handled scalar in vq_fin.
constexpr int ENC_NV4 = (int)((ENC_ELEMS - 4) / 4);    // 33554431 quads

constexpr int ENC_BLOCKS = 2048;
constexpr int ENC_CHUNK  = (ENC_NV4 + ENC_BLOCKS - 1) / ENC_BLOCKS;  // 16384 quads = 1 MB/block
constexpr int MAIN_BLOCKS = 2048;
constexpr int MAIN_CHUNK  = (NTOT / 4) / MAIN_BLOCKS;  // 1024 quads = 16 KB/block

typedef float v4f __attribute__((ext_vector_type(4)));

// Main fused kernel: gather codebook rows, write quantized (BCHW), accumulate loss.
// Block-linear partitioning: each block owns one contiguous 16 KB range.
__global__ __launch_bounds__(256) void vq_main(const float* __restrict__ input1,
                                               const int*   __restrict__ x_tilde,
                                               const float* __restrict__ weight,
                                               float* __restrict__ out,   // d_out base
                                               float* __restrict__ acc) { // d_ws accumulator
    float local = 0.f;
    const int base = blockIdx.x * MAIN_CHUNK;
    for (int i = threadIdx.x; i < MAIN_CHUNK; i += 256) {
        const int g  = base + i;
        const int f  = g << 2;
        const int b  = f >> 18;          // C*H*W = 2^18
        const int c  = (f >> 12) & 63;   // H*W   = 2^12
        const int n0 = (b << 12) | (f & 4095);   // spatial index, multiple of 4
        const int4   t4 = *reinterpret_cast<const int4*>(x_tilde + n0);
        const float4 x4 = *reinterpret_cast<const float4*>(input1 + f);
        const float q0 = weight[(t4.x << 6) | c];
        const float q1 = weight[(t4.y << 6) | c];
        const float q2 = weight[(t4.z << 6) | c];
        const float q3 = weight[(t4.w << 6) | c];
        const float d0 = q0 - x4.x, d1 = q1 - x4.y, d2 = q2 - x4.z, d3 = q3 - x4.w;
        out[OFF_Q + f + 0] = x4.x + d0;  // straight-through: x + (q - x)
        out[OFF_Q + f + 1] = x4.y + d1;
        out[OFF_Q + f + 2] = x4.z + d2;
        out[OFF_Q + f + 3] = x4.w + d3;
        local += d0 * d0 + d1 * d1 + d2 * d2 + d3 * d3;
    }
    // wave64 reduce
    for (int o = 32; o > 0; o >>= 1) local += __shfl_down(local, o);
    __shared__ float sm[4];
    const int lane = threadIdx.x & 63, wid = threadIdx.x >> 6;
    if (lane == 0) sm[wid] = local;
    __syncthreads();
    if (threadIdx.x == 0) {
        atomicAdd(acc, sm[0] + sm[1] + sm[2] + sm[3]);
    }
}

// Fused one-hot fill: writes the entire encodings interior (zeros AND ones).
// Block-contiguous chunks (1 MB per block, threads stride 4 KB within the chunk),
// plain (cached) 16B stores — mirrors the 6.5 TB/s fillBufferAligned access shape.
__global__ __launch_bounds__(256) void vq_enc_fill(const int* __restrict__ x_tilde,
                                                   float* __restrict__ out) {
    const int base = blockIdx.x * ENC_CHUNK;
    float* __restrict__ enc = out + OFF_ENC;
    for (int i = threadIdx.x; i < ENC_CHUNK; i += 256) {
        const int g = base + i;
        if (g >= ENC_NV4) break;              // only the final quad of the last block
        const int e0 = (g << 2) + 3;          // element index within encodings (16B aligned)
        const int n  = e0 >> 10;              // row
        const int k0 = e0 & 1023;             // col of first element
        const int t  = x_tilde[n];            // wave-uniform (scalar load)
        v4f v;
        if (k0 != 1023) {                     // whole quad inside row n (255/256 case)
            v.x = (t == k0    ) ? 1.f : 0.f;
            v.y = (t == k0 + 1) ? 1.f : 0.f;
            v.z = (t == k0 + 2) ? 1.f : 0.f;
            v.w = (t == k0 + 3) ? 1.f : 0.f;
        } else {                              // quad straddles rows n / n+1
            const int t1 = x_tilde[n + 1];
            v.x = (t  == 1023) ? 1.f : 0.f;
            v.y = (t1 == 0   ) ? 1.f : 0.f;
            v.z = (t1 == 1   ) ? 1.f : 0.f;
            v.w = (t1 == 2   ) ? 1.f : 0.f;
        }
        *reinterpret_cast<v4f*>(enc + e0) = v;
    }
}

// Finalize: loss scalar, input2_KL passthrough, and the 4 edge elements the
// aligned fill skipped (cols 0..2 of row 0; col 1023 of the last row).
__global__ void vq_fin(const int* __restrict__ x_tilde,
                       const float* __restrict__ acc,
                       const float* __restrict__ kl,
                       float* __restrict__ out) {
    const int t = threadIdx.x;
    if (t < 32) out[1 + t] = kl[t];
    if (t == 32) out[0] = 1.25f * (*acc) / (float)NTOT;
    if (t == 33) {
        const int t0 = x_tilde[0];
        out[OFF_ENC + 0] = (t0 == 0) ? 1.f : 0.f;
        out[OFF_ENC + 1] = (t0 == 1) ? 1.f : 0.f;
        out[OFF_ENC + 2] = (t0 == 2) ? 1.f : 0.f;
        const int tl = x_tilde[NSP - 1];
        out[OFF_ENC + (int)ENC_ELEMS - 1] = (tl == 1023) ? 1.f : 0.f;
    }
}

extern "C" void kernel_launch(void* const* d_in, const int* in_sizes, int n_in,
                              void* d_out, int out_size, void* d_ws, size_t ws_size,
                              hipStream_t stream) {
    const float* input1 = (const float*)d_in[0];
    const float* kl     = (const float*)d_in[1];
    const float* weight = (const float*)d_in[2];
    const int*   x_til  = (const int*)d_in[3];
    float* out = (float*)d_out;
    float* acc = (float*)d_ws;

    (void)hipMemsetAsync(acc, 0, sizeof(float), stream);

    vq_main<<<MAIN_BLOCKS, 256, 0, stream>>>(input1, x_til, weight, out, acc);
    vq_enc_fill<<<ENC_BLOCKS, 256, 0, stream>>>(x_til, out);
    vq_fin<<<1, 64, 0, stream>>>(x_til, acc, kl, out);
}

// Round 7
// 169.762 us; speedup vs baseline: 1.2161x; 1.2161x over previous
//
#include <hip/hip_runtime.h>

// Problem constants
constexpr int B_ = 32, C_ = 64, H_ = 64, W_ = 64, K_ = 1024;
constexpr int NTOT = B_ * C_ * H_ * W_;          // 8388608 elements of input1/quantized
constexpr int NSP  = B_ * H_ * W_;               // 131072 spatial positions
// d_out float offsets: [0]=loss, [1..32]=input2_KL, [33..33+NTOT)=quantized(BCHW),
// [OFF_ENC .. OFF_ENC+NSP*K)=encodings
constexpr int OFF_Q   = 33;
constexpr int OFF_ENC = OFF_Q + NTOT;            // 8388641 (byte 33554564 == 4 mod 64)
constexpr long long ENC_ELEMS = (long long)NSP * K_;   // 134217728 (2^27)
// (OFF_ENC + 15)*4 = 33554624 == 0 mod 64: zero-fill starts 64B-LINE-aligned.
// Head elements 0..14 (row 0, cols 0..14) and the final element (last row, col
// 1023) are written scalar in vq_scatter_fin.
constexpr int ENC_HEAD = 15;
constexpr int ENC_NQ = (int)((ENC_ELEMS - ENC_HEAD - 1) / 4);   // 33554428 quads
constexpr int ZERO_BLOCKS = (ENC_NQ + 255) / 256;               // 131072 blocks

constexpr int MAIN_BLOCKS = 2048;
constexpr int MAIN_CHUNK  = (NTOT / 4) / MAIN_BLOCKS;  // 1024 quads = 16 KB/block

typedef float v4f __attribute__((ext_vector_type(4)));

// Main fused kernel: gather codebook rows, write quantized (BCHW), accumulate loss.
__global__ __launch_bounds__(256) void vq_main(const float* __restrict__ input1,
                                               const int*   __restrict__ x_tilde,
                                               const float* __restrict__ weight,
                                               float* __restrict__ out,   // d_out base
                                               float* __restrict__ acc) { // d_ws accumulator
    float local = 0.f;
    const int base = blockIdx.x * MAIN_CHUNK;
    for (int i = threadIdx.x; i < MAIN_CHUNK; i += 256) {
        const int g  = base + i;
        const int f  = g << 2;
        const int b  = f >> 18;          // C*H*W = 2^18
        const int c  = (f >> 12) & 63;   // H*W   = 2^12
        const int n0 = (b << 12) | (f & 4095);   // spatial index, multiple of 4
        const int4   t4 = *reinterpret_cast<const int4*>(x_tilde + n0);
        const float4 x4 = *reinterpret_cast<const float4*>(input1 + f);
        const float q0 = weight[(t4.x << 6) | c];
        const float q1 = weight[(t4.y << 6) | c];
        const float q2 = weight[(t4.z << 6) | c];
        const float q3 = weight[(t4.w << 6) | c];
        const float d0 = q0 - x4.x, d1 = q1 - x4.y, d2 = q2 - x4.z, d3 = q3 - x4.w;
        out[OFF_Q + f + 0] = x4.x + d0;  // straight-through: x + (q - x)
        out[OFF_Q + f + 1] = x4.y + d1;
        out[OFF_Q + f + 2] = x4.z + d2;
        out[OFF_Q + f + 3] = x4.w + d3;
        local += d0 * d0 + d1 * d1 + d2 * d2 + d3 * d3;
    }
    // wave64 reduce
    for (int o = 32; o > 0; o >>= 1) local += __shfl_down(local, o);
    __shared__ float sm[4];
    const int lane = threadIdx.x & 63, wid = threadIdx.x >> 6;
    if (lane == 0) sm[wid] = local;
    __syncthreads();
    if (threadIdx.x == 0) {
        atomicAdd(acc, sm[0] + sm[1] + sm[2] + sm[3]);
    }
}

// Pure zero-fill of the encodings interior — exact replica of the rocclr
// fillBufferAligned shape that measures 6.7 TB/s: one 16B store per thread,
// no loop, no loads, 64B-line-phase-aligned stream, 8-VGPR-class kernel.
__global__ __launch_bounds__(256) void vq_zero(float* __restrict__ out) {
    const int g = blockIdx.x * 256 + threadIdx.x;
    if (g < ENC_NQ) {
        const v4f z = {0.f, 0.f, 0.f, 0.f};
        *reinterpret_cast<v4f*>(out + OFF_ENC + ENC_HEAD + (g << 2)) = z;
    }
}

// Scatter the NSP ones into the zeroed region, patch the head/tail elements the
// line-aligned fill skipped, and finalize loss + KL passthrough.
__global__ __launch_bounds__(256) void vq_scatter_fin(const int* __restrict__ x_tilde,
                                                      const float* __restrict__ acc,
                                                      const float* __restrict__ kl,
                                                      float* __restrict__ out) {
    const int bid = blockIdx.x;
    if (bid < NSP / 256) {
        const int n = (bid << 8) + threadIdx.x;
        const int t = x_tilde[n];
        out[OFF_ENC + (n << 10) + t] = 1.0f;
    } else {
        const int tt = threadIdx.x;
        if (tt < 32) out[1 + tt] = kl[tt];
        if (tt == 32) out[0] = 1.25f * (*acc) / (float)NTOT;
        if (tt == 33) {
            // head: cols 0..14 of row 0 (benign same-value race with scatter n=0)
            const int t0 = x_tilde[0];
            #pragma unroll
            for (int j = 0; j < ENC_HEAD; ++j)
                out[OFF_ENC + j] = (t0 == j) ? 1.f : 0.f;
            // tail: col 1023 of the last row
            const int tl = x_tilde[NSP - 1];
            out[OFF_ENC + (int)ENC_ELEMS - 1] = (tl == 1023) ? 1.f : 0.f;
        }
    }
}

extern "C" void kernel_launch(void* const* d_in, const int* in_sizes, int n_in,
                              void* d_out, int out_size, void* d_ws, size_t ws_size,
                              hipStream_t stream) {
    const float* input1 = (const float*)d_in[0];
    const float* kl     = (const float*)d_in[1];
    const float* weight = (const float*)d_in[2];
    const int*   x_til  = (const int*)d_in[3];
    float* out = (float*)d_out;
    float* acc = (float*)d_ws;

    (void)hipMemsetAsync(acc, 0, sizeof(float), stream);

    vq_main<<<MAIN_BLOCKS, 256, 0, stream>>>(input1, x_til, weight, out, acc);
    vq_zero<<<ZERO_BLOCKS, 256, 0, stream>>>(out);
    vq_scatter_fin<<<NSP / 256 + 1, 256, 0, stream>>>(x_til, acc, kl, out);
}

// Round 8
// 143.503 us; speedup vs baseline: 1.4386x; 1.1830x over previous
//
#include <hip/hip_runtime.h>

// Problem constants
constexpr int B_ = 32, C_ = 64, H_ = 64, W_ = 64, K_ = 1024;
constexpr int NTOT = B_ * C_ * H_ * W_;          // 8388608 elements of input1/quantized
constexpr int NSP  = B_ * H_ * W_;               // 131072 spatial positions
// d_out float offsets: [0]=loss, [1..32]=input2_KL, [33..33+NTOT)=quantized(BCHW),
// [OFF_ENC .. OFF_ENC+NSP*K)=encodings
constexpr int OFF_Q   = 33;
constexpr int OFF_ENC = OFF_Q + NTOT;            // 8388641 (byte 33554564 == 4 mod 64)
constexpr long long ENC_ELEMS = (long long)NSP * K_;   // 134217728 (2^27)
// (OFF_ENC + 15)*4 == 0 mod 64: zero-fill starts 64B-LINE-aligned.
// Head elements 0..14 and the final element are patched inside vq_main.
constexpr int ENC_HEAD = 15;
constexpr int ENC_NQ = (int)((ENC_ELEMS - ENC_HEAD - 1) / 4);   // 33554428 quads
constexpr int ZERO_BLOCKS = (ENC_NQ + 255) / 256;               // 131072 blocks

typedef float v4f __attribute__((ext_vector_type(4)));

// Pure zero-fill of the encodings interior — replica of the rocclr
// fillBufferAligned shape (6.5+ TB/s): one 16B store per thread, no loop,
// no loads, 64B-line-phase-aligned stream. Also zeroes the loss accumulator
// (runs before vq_main in stream order).
__global__ __launch_bounds__(256) void vq_zero(float* __restrict__ out,
                                               float* __restrict__ acc) {
    const int g = blockIdx.x * 256 + threadIdx.x;
    if (g == 0) *acc = 0.f;
    if (g < ENC_NQ) {
        const v4f z = {0.f, 0.f, 0.f, 0.f};
        *reinterpret_cast<v4f*>(out + OFF_ENC + ENC_HEAD + (g << 2)) = z;
    }
}

// Transposed main kernel: one thread per spatial position n. Loads the full
// codebook row for t = x_tilde[n] as 4 fully-used 64B lines (vs the old
// per-element gather that pulled 64B per 4B used = 2.1 GB of L1-fill traffic).
// Loops over the 64 channels; per c the wave's 64 lanes touch 256B contiguous
// in input1/out (coalesced). Also scatters this row's 1.0 into the encodings
// (zeroed by vq_zero, which runs earlier in the stream) and accumulates loss.
__global__ __launch_bounds__(256) void vq_main(const float* __restrict__ input1,
                                               const int*   __restrict__ x_tilde,
                                               const float* __restrict__ weight,
                                               float* __restrict__ out,   // d_out base
                                               float* __restrict__ acc) { // d_ws accumulator
    const int n  = blockIdx.x * 256 + threadIdx.x;   // [0, NSP)
    const int b  = n >> 12;          // H*W = 4096
    const int hw = n & 4095;
    const int t  = x_tilde[n];
    const float* __restrict__ wrow = weight + (t << 6);
    const float* __restrict__ xin  = input1 + (b << 18) + hw;
    float* __restrict__ qout = out + OFF_Q + (b << 18) + hw;

    float local = 0.f;
    #pragma unroll
    for (int c0 = 0; c0 < 64; c0 += 16) {
        // one 64B line of the codebook row, fully used
        const float4 w0 = *reinterpret_cast<const float4*>(wrow + c0);
        const float4 w1 = *reinterpret_cast<const float4*>(wrow + c0 + 4);
        const float4 w2 = *reinterpret_cast<const float4*>(wrow + c0 + 8);
        const float4 w3 = *reinterpret_cast<const float4*>(wrow + c0 + 12);
        const float wv[16] = {w0.x, w0.y, w0.z, w0.w, w1.x, w1.y, w1.z, w1.w,
                              w2.x, w2.y, w2.z, w2.w, w3.x, w3.y, w3.z, w3.w};
        #pragma unroll
        for (int j = 0; j < 16; ++j) {
            const int c = c0 + j;
            const float x = xin[c << 12];
            const float d = wv[j] - x;
            qout[c << 12] = x + d;   // straight-through: x + (q - x)
            local += d * d;
        }
    }

    // scatter this row's one-hot 1.0 (region already zeroed by vq_zero)
    out[OFF_ENC + (n << 10) + t] = 1.0f;
    // patch the edges the 64B-aligned zero-fill skipped
    if (n == 0) {
        #pragma unroll
        for (int j = 0; j < ENC_HEAD; ++j)
            out[OFF_ENC + j] = (t == j) ? 1.f : 0.f;   // benign same-value overlap
    }
    if (n == NSP - 1) {
        out[OFF_ENC + (int)ENC_ELEMS - 1] = (t == 1023) ? 1.f : 0.f;
    }

    // wave64 reduce + one atomic per block
    for (int o = 32; o > 0; o >>= 1) local += __shfl_down(local, o);
    __shared__ float sm[4];
    const int lane = threadIdx.x & 63, wid = threadIdx.x >> 6;
    if (lane == 0) sm[wid] = local;
    __syncthreads();
    if (threadIdx.x == 0) {
        atomicAdd(acc, sm[0] + sm[1] + sm[2] + sm[3]);
    }
}

// Finalize: loss scalar + input2_KL passthrough.
__global__ void vq_fin(const float* __restrict__ acc,
                       const float* __restrict__ kl,
                       float* __restrict__ out) {
    const int t = threadIdx.x;
    if (t < 32) out[1 + t] = kl[t];
    if (t == 32) out[0] = 1.25f * (*acc) / (float)NTOT;
}

extern "C" void kernel_launch(void* const* d_in, const int* in_sizes, int n_in,
                              void* d_out, int out_size, void* d_ws, size_t ws_size,
                              hipStream_t stream) {
    const float* input1 = (const float*)d_in[0];
    const float* kl     = (const float*)d_in[1];
    const float* weight = (const float*)d_in[2];
    const int*   x_til  = (const int*)d_in[3];
    float* out = (float*)d_out;
    float* acc = (float*)d_ws;

    vq_zero<<<ZERO_BLOCKS, 256, 0, stream>>>(out, acc);
    vq_main<<<NSP / 256, 256, 0, stream>>>(input1, x_til, weight, out, acc);
    vq_fin<<<1, 64, 0, stream>>>(acc, kl, out);
}

// Round 9
// 137.606 us; speedup vs baseline: 1.5003x; 1.0429x over previous
//
#include <hip/hip_runtime.h>

// Problem constants
constexpr int B_ = 32, C_ = 64, H_ = 64, W_ = 64, K_ = 1024;
constexpr int NTOT = B_ * C_ * H_ * W_;          // 8388608 elements of input1/quantized
constexpr int NSP  = B_ * H_ * W_;               // 131072 spatial positions
// d_out float offsets: [0]=loss, [1..32]=input2_KL, [33..33+NTOT)=quantized(BCHW),
// [OFF_ENC .. OFF_ENC+NSP*K)=encodings
constexpr int OFF_Q   = 33;
constexpr int OFF_ENC = OFF_Q + NTOT;            // 8388641 (byte 33554564 == 4 mod 64)
constexpr long long ENC_ELEMS = (long long)NSP * K_;   // 134217728 (2^27)
// (OFF_ENC + 15)*4 == 0 mod 64: computed fill starts 64B-LINE-aligned.
// Head (row 0, cols 0..14) and tail (last row, col 1023) patched in vq_fin.
constexpr int ENC_HEAD = 15;
constexpr int ENC_NQ = (int)((ENC_ELEMS - ENC_HEAD - 1) / 4);   // 33554428 quads
constexpr int ENC_BLOCKS = (ENC_NQ + 255) / 256;                // 131072 blocks

typedef float v4f __attribute__((ext_vector_type(4)));

// Computed one-hot fill in the exact rocclr fillBufferAligned shape that
// sustains 6.5+ TB/s (R7): ONE 16B store per thread, NO loop, no load in a
// store-dependency chain. Block b covers quads [256b, 256b+256) = elements
// [15+1024b, 15+1024(b+1)) — i.e. cols 15..1023 of row b + cols 0..14 of row
// b+1 — so the only loads are two wave-uniform (broadcast) x_tilde words.
__global__ __launch_bounds__(256) void vq_enc(const int* __restrict__ x_tilde,
                                              float* __restrict__ out) {
    const int b  = blockIdx.x;
    const int qi = b * 256 + threadIdx.x;
    if (qi >= ENC_NQ) return;                 // 4 idle threads in the last block
    const int t0 = x_tilde[b];
    const int t1 = x_tilde[(b + 1 < NSP) ? b + 1 : NSP - 1];  // unused when b is last
    const int col0 = ENC_HEAD + (threadIdx.x << 2);           // 15..1035, rel. row b
    v4f v;
    #pragma unroll
    for (int j = 0; j < 4; ++j) {
        const int col = col0 + j;
        ((float*)&v)[j] = (col < 1024) ? ((t0 == col) ? 1.f : 0.f)
                                       : ((t1 == col - 1024) ? 1.f : 0.f);
    }
    *reinterpret_cast<v4f*>(out + OFF_ENC + ENC_HEAD + (qi << 2)) = v;
}

// Transposed main kernel, 4-way channel split for occupancy: thread handles
// (n, one 16-channel chunk). Per wave all 64 lanes share the chunk and have
// consecutive n -> input1/out accesses are coalesced 256B; the codebook row
// chunk is one fully-used 64B line (L2-resident, codebook = 256 KB).
__global__ __launch_bounds__(256) void vq_main(const float* __restrict__ input1,
                                               const int*   __restrict__ x_tilde,
                                               const float* __restrict__ weight,
                                               float* __restrict__ out,   // d_out base
                                               float* __restrict__ acc) { // d_ws accumulator
    const int tid = threadIdx.x;
    const int n   = blockIdx.x * 64 + (tid & 63);    // [0, NSP)
    const int cq  = tid >> 6;                        // 0..3 -> channels 16cq..16cq+15
    const int b   = n >> 12;                         // H*W = 4096
    const int hw  = n & 4095;
    const int t   = x_tilde[n];
    const float* __restrict__ wrow = weight + (t << 6) + (cq << 4);
    const float* __restrict__ xin  = input1 + (b << 18) + (cq << 16) + hw;
    float* __restrict__ qout = out + OFF_Q + (b << 18) + (cq << 16) + hw;

    const float4 w0 = *reinterpret_cast<const float4*>(wrow);
    const float4 w1 = *reinterpret_cast<const float4*>(wrow + 4);
    const float4 w2 = *reinterpret_cast<const float4*>(wrow + 8);
    const float4 w3 = *reinterpret_cast<const float4*>(wrow + 12);
    const float wv[16] = {w0.x, w0.y, w0.z, w0.w, w1.x, w1.y, w1.z, w1.w,
                          w2.x, w2.y, w2.z, w2.w, w3.x, w3.y, w3.z, w3.w};
    float local = 0.f;
    #pragma unroll
    for (int j = 0; j < 16; ++j) {
        const float x = xin[j << 12];
        const float d = wv[j] - x;
        qout[j << 12] = x + d;       // straight-through: x + (q - x)
        local += d * d;
    }

    // wave64 reduce + one atomic per block
    for (int o = 32; o > 0; o >>= 1) local += __shfl_down(local, o);
    __shared__ float sm[4];
    const int lane = tid & 63, wid = tid >> 6;
    if (lane == 0) sm[wid] = local;
    __syncthreads();
    if (tid == 0) {
        atomicAdd(acc, sm[0] + sm[1] + sm[2] + sm[3]);
    }
}

// Finalize: loss scalar, input2_KL passthrough, and the 16 edge elements the
// line-aligned computed fill skipped.
__global__ void vq_fin(const int* __restrict__ x_tilde,
                       const float* __restrict__ acc,
                       const float* __restrict__ kl,
                       float* __restrict__ out) {
    const int t = threadIdx.x;
    if (t < 32) out[1 + t] = kl[t];
    if (t == 32) out[0] = 1.25f * (*acc) / (float)NTOT;
    if (t == 33) {
        const int t0 = x_tilde[0];
        #pragma unroll
        for (int j = 0; j < ENC_HEAD; ++j)
            out[OFF_ENC + j] = (t0 == j) ? 1.f : 0.f;      // row 0, cols 0..14
        const int tl = x_tilde[NSP - 1];
        out[OFF_ENC + (int)ENC_ELEMS - 1] = (tl == 1023) ? 1.f : 0.f;
    }
}

extern "C" void kernel_launch(void* const* d_in, const int* in_sizes, int n_in,
                              void* d_out, int out_size, void* d_ws, size_t ws_size,
                              hipStream_t stream) {
    const float* input1 = (const float*)d_in[0];
    const float* kl     = (const float*)d_in[1];
    const float* weight = (const float*)d_in[2];
    const int*   x_til  = (const int*)d_in[3];
    float* out = (float*)d_out;
    float* acc = (float*)d_ws;

    (void)hipMemsetAsync(acc, 0, sizeof(float), stream);

    vq_main<<<NSP / 64, 256, 0, stream>>>(input1, x_til, weight, out, acc);
    vq_enc<<<ENC_BLOCKS, 256, 0, stream>>>(x_til, out);
    vq_fin<<<1, 64, 0, stream>>>(x_til, acc, kl, out);
}

// Round 10
// 132.456 us; speedup vs baseline: 1.5586x; 1.0389x over previous
//
#include <hip/hip_runtime.h>

// Problem constants
constexpr int B_ = 32, C_ = 64, H_ = 64, W_ = 64, K_ = 1024;
constexpr int NTOT = B_ * C_ * H_ * W_;          // 8388608 elements of input1/quantized
constexpr int NSP  = B_ * H_ * W_;               // 131072 spatial positions
// d_out float offsets: [0]=loss, [1..32]=input2_KL, [33..33+NTOT)=quantized(BCHW),
// [OFF_ENC .. OFF_ENC+NSP*K)=encodings
constexpr int OFF_Q   = 33;
constexpr int OFF_ENC = OFF_Q + NTOT;            // 8388641 (byte 33554564 == 4 mod 64)
constexpr long long ENC_ELEMS = (long long)NSP * K_;   // 134217728 (2^27)
// (OFF_ENC + 15)*4 == 0 mod 64: computed fill starts 64B-LINE-aligned.
// Head (row 0, cols 0..14) and tail (last row, col 1023) patched in vq_fin.
constexpr int ENC_HEAD = 15;
constexpr int ENC_NQ = (int)((ENC_ELEMS - ENC_HEAD - 1) / 4);   // 33554428 quads
constexpr int ENC_BLOCKS = (ENC_NQ + 255) / 256;                // 131072 blocks

constexpr int MAIN_BLOCKS  = NSP / 64;                          // 2048 blocks
constexpr int TOTAL_BLOCKS = MAIN_BLOCKS + ENC_BLOCKS;          // 133120

typedef float v4f __attribute__((ext_vector_type(4)));

// Fused kernel. Blocks [0, MAIN_BLOCKS): quantized+loss (R9 vq_main, unchanged).
// Blocks [MAIN_BLOCKS, TOTAL_BLOCKS): computed one-hot fill (R9 vq_enc, unchanged).
// The two parts write disjoint d_out regions and only share x_tilde reads, so
// they are safely concurrent; fusing removes the stream-order serialization
// that previously put main's full duration in front of the BW-bound fill.
__global__ __launch_bounds__(256) void vq_fused(const float* __restrict__ input1,
                                                const int*   __restrict__ x_tilde,
                                                const float* __restrict__ weight,
                                                float* __restrict__ out,   // d_out base
                                                float* __restrict__ acc) { // d_ws accumulator
    const int bid = blockIdx.x;
    if (bid >= MAIN_BLOCKS) {
        // ---- encodings fill path (rocclr fill shape: one 16B store/thread) ----
        const int b  = bid - MAIN_BLOCKS;
        const int qi = b * 256 + threadIdx.x;
        if (qi >= ENC_NQ) return;             // 4 idle threads in the last block
        const int t0 = x_tilde[b];
        const int t1 = x_tilde[(b + 1 < NSP) ? b + 1 : NSP - 1];
        const int col0 = ENC_HEAD + (threadIdx.x << 2);        // 15..1035 rel. row b
        v4f v;
        #pragma unroll
        for (int j = 0; j < 4; ++j) {
            const int col = col0 + j;
            ((float*)&v)[j] = (col < 1024) ? ((t0 == col) ? 1.f : 0.f)
                                           : ((t1 == col - 1024) ? 1.f : 0.f);
        }
        *reinterpret_cast<v4f*>(out + OFF_ENC + ENC_HEAD + (qi << 2)) = v;
        return;
    }

    // ---- quantized + loss path (transposed gather, 4-way channel split) ----
    const int tid = threadIdx.x;
    const int n   = bid * 64 + (tid & 63);           // [0, NSP)
    const int cq  = tid >> 6;                        // 0..3 -> channels 16cq..16cq+15
    const int b   = n >> 12;                         // H*W = 4096
    const int hw  = n & 4095;
    const int t   = x_tilde[n];
    const float* __restrict__ wrow = weight + (t << 6) + (cq << 4);
    const float* __restrict__ xin  = input1 + (b << 18) + (cq << 16) + hw;
    float* __restrict__ qout = out + OFF_Q + (b << 18) + (cq << 16) + hw;

    const float4 w0 = *reinterpret_cast<const float4*>(wrow);
    const float4 w1 = *reinterpret_cast<const float4*>(wrow + 4);
    const float4 w2 = *reinterpret_cast<const float4*>(wrow + 8);
    const float4 w3 = *reinterpret_cast<const float4*>(wrow + 12);
    const float wv[16] = {w0.x, w0.y, w0.z, w0.w, w1.x, w1.y, w1.z, w1.w,
                          w2.x, w2.y, w2.z, w2.w, w3.x, w3.y, w3.z, w3.w};
    float local = 0.f;
    #pragma unroll
    for (int j = 0; j < 16; ++j) {
        const float x = xin[j << 12];
        const float d = wv[j] - x;
        qout[j << 12] = x + d;       // straight-through: x + (q - x)
        local += d * d;
    }

    // wave64 reduce + one atomic per block
    for (int o = 32; o > 0; o >>= 1) local += __shfl_down(local, o);
    __shared__ float sm[4];
    const int lane = tid & 63, wid = tid >> 6;
    if (lane == 0) sm[wid] = local;
    __syncthreads();
    if (tid == 0) {
        atomicAdd(acc, sm[0] + sm[1] + sm[2] + sm[3]);
    }
}

// Finalize: loss scalar, input2_KL passthrough, and the 16 edge elements the
// line-aligned computed fill skipped.
__global__ void vq_fin(const int* __restrict__ x_tilde,
                       const float* __restrict__ acc,
                       const float* __restrict__ kl,
                       float* __restrict__ out) {
    const int t = threadIdx.x;
    if (t < 32) out[1 + t] = kl[t];
    if (t == 32) out[0] = 1.25f * (*acc) / (float)NTOT;
    if (t == 33) {
        const int t0 = x_tilde[0];
        #pragma unroll
        for (int j = 0; j < ENC_HEAD; ++j)
            out[OFF_ENC + j] = (t0 == j) ? 1.f : 0.f;      // row 0, cols 0..14
        const int tl = x_tilde[NSP - 1];
        out[OFF_ENC + (int)ENC_ELEMS - 1] = (tl == 1023) ? 1.f : 0.f;
    }
}

extern "C" void kernel_launch(void* const* d_in, const int* in_sizes, int n_in,
                              void* d_out, int out_size, void* d_ws, size_t ws_size,
                              hipStream_t stream) {
    const float* input1 = (const float*)d_in[0];
    const float* kl     = (const float*)d_in[1];
    const float* weight = (const float*)d_in[2];
    const int*   x_til  = (const int*)d_in[3];
    float* out = (float*)d_out;
    float* acc = (float*)d_ws;

    (void)hipMemsetAsync(acc, 0, sizeof(float), stream);

    vq_fused<<<TOTAL_BLOCKS, 256, 0, stream>>>(input1, x_til, weight, out, acc);
    vq_fin<<<1, 64, 0, stream>>>(x_til, acc, kl, out);
}